// Round 15
// baseline (2092.400 us; speedup 1.0000x reference)
//
#include <hip/hip_runtime.h>
#include <stdint.h>

#define BB 64
#define TT 256
#define VV 32000
#define DD 512
#define HH 1024
#define FH 4096

#define UCOL 1040                 // padded LDS col stride (i8, 1024+16)
#define ULDS (128 * UCOL)         // 133120
#define LSTM_LDS (ULDS + 1024)
#define RSTRIDE (TT * FH * 2)
#define SENT 0x80808080u

typedef float f32x4 __attribute__((ext_vector_type(4)));
typedef int   i32x4 __attribute__((ext_vector_type(4)));
typedef __bf16 bf16x8 __attribute__((ext_vector_type(8)));

typedef __attribute__((address_space(1))) void void_g;
typedef __attribute__((address_space(3))) void void_l;

static __device__ __forceinline__ void gload_lds16(const void* g, void* l) {
  __builtin_amdgcn_global_load_lds((const void_g*)g, (void_l*)l, 16, 0, 0);
}

static __device__ __forceinline__ unsigned short f2bf(float f) {
  union { float f; unsigned u; } x; x.f = f;
  unsigned r = x.u + 0x7FFFu + ((x.u >> 16) & 1u);
  return (unsigned short)(r >> 16);
}
static __device__ __forceinline__ float bf2f(unsigned short s) {
  union { unsigned u; float f; } x; x.u = ((unsigned)s) << 16;
  return x.f;
}
static __device__ __forceinline__ i32x4 as_i32x4(uint4 v) {
  union { uint4 u; i32x4 i; } x; x.u = v; return x.i;
}
static __device__ __forceinline__ float sigm(float x) {
  return 1.f / (1.f + __expf(-x));
}
static __device__ __forceinline__ float tanh_f(float x) {
  x = fminf(15.f, fmaxf(-15.f, x));
  float e = __expf(2.f * x);
  return (e - 1.f) / (e + 1.f);
}

// ---------------- prep kernels ----------------

__global__ void k_cast_emb(const float* __restrict__ src, unsigned short* __restrict__ dst) {
  size_t i = ((size_t)blockIdx.x * 256 + threadIdx.x) * 8;
  float4 a = *(const float4*)(src + i);
  float4 b = *(const float4*)(src + i + 4);
  uint4 o;
  o.x = (unsigned)f2bf(a.x) | ((unsigned)f2bf(a.y) << 16);
  o.y = (unsigned)f2bf(a.z) | ((unsigned)f2bf(a.w) << 16);
  o.z = (unsigned)f2bf(b.x) | ((unsigned)f2bf(b.y) << 16);
  o.w = (unsigned)f2bf(b.z) | ((unsigned)f2bf(b.w) << 16);
  *(uint4*)(dst + i) = o;
}

// Plain transpose: Wt[n][k] bf16
__global__ void k_prep_w(const float* __restrict__ Wsrc, unsigned short* __restrict__ Wt) {
  int n = blockIdx.x;
  int k0 = threadIdx.x * 4;
  unsigned short q0 = f2bf(Wsrc[(size_t)(k0 + 0) * FH + n]);
  unsigned short q1 = f2bf(Wsrc[(size_t)(k0 + 1) * FH + n]);
  unsigned short q2 = f2bf(Wsrc[(size_t)(k0 + 2) * FH + n]);
  unsigned short q3 = f2bf(Wsrc[(size_t)(k0 + 3) * FH + n]);
  uint2 o;
  o.x = (unsigned)q0 | ((unsigned)q1 << 16);
  o.y = (unsigned)q2 | ((unsigned)q3 << 16);
  *(uint2*)((char*)Wt + (size_t)n * 1024 + (size_t)k0 * 2) = o;
}

// U int8 per-column quantization. Slice s (0..31), local col c (0..127):
// c = g*32 + m ; hidden = s*32 + m ; source col n = g*1024 + s*32 + m.
// Uq[s][c][k] i8 (col stride 1024), su[s*128+c] = maxcol / 127^2.
__global__ void k_prep_uq(const float* __restrict__ Usrc, char* __restrict__ Uq,
                          float* __restrict__ su) {
  __shared__ float red[4];
  int bid = blockIdx.x;
  int s = bid >> 7, c = bid & 127;
  int g = c >> 5, m = c & 31;
  int n = g * 1024 + s * 32 + m;
  int tid = threadIdx.x, lane = tid & 63, wid = tid >> 6;
  float v[4];
  float mx = 0.f;
  #pragma unroll
  for (int j = 0; j < 4; ++j) {
    v[j] = Usrc[(size_t)(tid * 4 + j) * FH + n];
    mx = fmaxf(mx, fabsf(v[j]));
  }
  #pragma unroll
  for (int off = 32; off; off >>= 1) mx = fmaxf(mx, __shfl_xor(mx, off));
  if (lane == 0) red[wid] = mx;
  __syncthreads();
  mx = fmaxf(fmaxf(red[0], red[1]), fmaxf(red[2], red[3]));
  float inv = mx > 0.f ? 127.f / mx : 0.f;
  unsigned pk = 0;
  #pragma unroll
  for (int j = 0; j < 4; ++j) {
    int q = __float2int_rn(v[j] * inv);
    pk |= ((unsigned)q & 255u) << (8 * j);
  }
  *(unsigned*)(Uq + (size_t)s * 131072 + (size_t)c * 1024 + tid * 4) = pk;
  if (tid == 0) su[s * 128 + c] = mx / 16129.f;
}

__global__ void k_mask(const int* __restrict__ tok, unsigned long long* __restrict__ mask64) {
  int t = threadIdx.x;
  unsigned long long m = 0;
  for (int b = 0; b < BB; ++b)
    m |= (unsigned long long)(tok[b * TT + t] != 0) << b;
  mask64[t] = m;
}

// ---------------- xW GEMM (gather fused) ----------------
// Output permuted: p = s*128 + m*4 + g  (4 gates adjacent per hidden)

__launch_bounds__(256)
__global__ void k_gemm_xw(const int* __restrict__ tok, const unsigned short* __restrict__ embb,
                          const unsigned short* __restrict__ Wt, const float* __restrict__ bsrc,
                          unsigned short* __restrict__ xw) {
  __shared__ char As[16384];
  __shared__ char Bs[16384];
  __shared__ int toks[128];
  int tid = threadIdx.x, lane = tid & 63, wid = tid >> 6;
  int bm = blockIdx.x >> 5, bn = blockIdx.x & 31;
  if (tid < 128) toks[tid] = tok[bm * 128 + tid];
  int wm = wid >> 1, wn = wid & 1;
  f32x4 vz = {0.f, 0.f, 0.f, 0.f};
  f32x4 acc[4][4];
  #pragma unroll
  for (int i = 0; i < 4; ++i)
    #pragma unroll
    for (int j = 0; j < 4; ++j) acc[i][j] = vz;

  int kls = (lane >> 4) * 16;
  for (int ks = 0; ks < 8; ++ks) {
    __syncthreads();
    #pragma unroll
    for (int c = 0; c < 4; ++c) {
      int o = wid * 4096 + c * 1024 + lane * 16;
      int m = o >> 7, kl = o & 127;
      const char* ga = (const char*)embb + (size_t)toks[m] * 1024 + ks * 128 + (kl ^ ((m & 7) << 4));
      gload_lds16(ga, As + o);
      const char* gb = (const char*)Wt + (size_t)(bn * 128 + m) * 1024 + ks * 128 + (kl ^ ((m & 7) << 4));
      gload_lds16(gb, Bs + o);
    }
    asm volatile("s_waitcnt vmcnt(0)" ::: "memory");
    __syncthreads();
    #pragma unroll
    for (int tk = 0; tk < 2; ++tk) {
      bf16x8 af[4], bf[4];
      int kb = tk * 64 + kls;
      #pragma unroll
      for (int mt = 0; mt < 4; ++mt) {
        int m = wm * 64 + mt * 16 + (lane & 15);
        af[mt] = *(const bf16x8*)(As + m * 128 + (kb ^ ((m & 7) << 4)));
      }
      #pragma unroll
      for (int nt = 0; nt < 4; ++nt) {
        int n = wn * 64 + nt * 16 + (lane & 15);
        bf[nt] = *(const bf16x8*)(Bs + n * 128 + (kb ^ ((n & 7) << 4)));
      }
      #pragma unroll
      for (int mt = 0; mt < 4; ++mt)
        #pragma unroll
        for (int nt = 0; nt < 4; ++nt)
          acc[mt][nt] = __builtin_amdgcn_mfma_f32_16x16x32_bf16(af[mt], bf[nt], acc[mt][nt], 0, 0, 0);
    }
  }
  #pragma unroll
  for (int nt = 0; nt < 4; ++nt) {
    int n = bn * 128 + wn * 64 + nt * 16 + (lane & 15);
    float bias = bsrc[n];
    int g = n >> 10, hid = n & 1023, s = hid >> 5, m = hid & 31;
    int p = s * 128 + m * 4 + g;
    #pragma unroll
    for (int mt = 0; mt < 4; ++mt) {
      #pragma unroll
      for (int r = 0; r < 4; ++r) {
        int row = bm * 128 + wm * 64 + mt * 16 + (lane >> 4) * 4 + r;
        xw[(size_t)row * FH + p] = f2bf(acc[mt][nt][r] + bias);
      }
    }
  }
}

// ---------------- persistent LSTM scan: 4 groups x 32 WGs, SENTINEL -------
// Same tiling as R13/R14 but NO flags: hseq is memset to 0x80 per launch;
// valid i8 h bytes are in [-127,127] so no written u32 equals 0x80808080.
// Producers fire ONE relaxed u32 store per lane and move on (no drain).
// Consumers poll their own 256B payload directly with 16 overlapped
// coherent dwordx4 loads (sc0 sc1) + vmcnt(0) inside one asm block; the
// poll load IS the data load.

#define GATE(R) do { \
  unsigned long long x_ = xg[R]; \
  float zi_ = (float)aI[R] * s0 + bf2f((unsigned short)(x_ & 0xFFFFu)); \
  float zf_ = (float)aF[R] * s1 + bf2f((unsigned short)((x_ >> 16) & 0xFFFFu)); \
  float zg_ = (float)aG[R] * s2 + bf2f((unsigned short)((x_ >> 32) & 0xFFFFu)); \
  float zo_ = (float)aO[R] * s3 + bf2f((unsigned short)((x_ >> 48) & 0xFFFFu)); \
  float I_ = sigm(zi_), F_ = sigm(zf_), G_ = tanh_f(zg_), O_ = sigm(zo_); \
  float cn_ = F_ * cst[R] + I_ * G_; \
  float hn_ = O_ * tanh_f(cn_); \
  if (!((mb >> (grp * 16 + lq * 4 + (R))) & 1ull)) { cn_ = cst[R]; hn_ = hst[R]; } \
  cst[R] = cn_; hst[R] = hn_; \
  hs[hh * 320 + (lq * 4 + (R)) * 20 + l15] = (char)__float2int_rn(hn_ * 127.f); \
  if (t == TT - 1) hfin[(size_t)(grp * 16 + lq * 4 + (R)) * 1024 + rank * 32 + hh * 16 + l15] = hn_; \
} while (0)

#define CHK(A) do { \
  mn = min(mn, (A).x ^ SENT); mn = min(mn, (A).y ^ SENT); \
  mn = min(mn, (A).z ^ SENT); mn = min(mn, (A).w ^ SENT); \
} while (0)

#define MFMA1(A, U) do { \
  i32x4 a_ = as_i32x4(A); \
  i32x4 b0_ = *(const i32x4*)(Us + bo0 + (U) * 64); \
  i32x4 b1_ = *(const i32x4*)(Us + bo1 + (U) * 64); \
  i32x4 b2_ = *(const i32x4*)(Us + bo2 + (U) * 64); \
  i32x4 b3_ = *(const i32x4*)(Us + bo3 + (U) * 64); \
  aI = __builtin_amdgcn_mfma_i32_16x16x64_i8(a_, b0_, aI, 0, 0, 0); \
  aF = __builtin_amdgcn_mfma_i32_16x16x64_i8(a_, b1_, aF, 0, 0, 0); \
  aG = __builtin_amdgcn_mfma_i32_16x16x64_i8(a_, b2_, aG, 0, 0, 0); \
  aO = __builtin_amdgcn_mfma_i32_16x16x64_i8(a_, b3_, aO, 0, 0, 0); \
} while (0)

__launch_bounds__(128, 1)
__global__ void k_lstm(const char* __restrict__ Uq, const float* __restrict__ su,
                       const unsigned short* __restrict__ xw,
                       const unsigned long long* __restrict__ mask64,
                       char* __restrict__ hseq, float* __restrict__ hfin) {
  extern __shared__ char smem[];
  char* Us = smem;
  char* hs = smem + ULDS;   // [2 waves][16 rows][20]
  int tid = threadIdx.x, lane = tid & 63, hh = tid >> 6;
  int l15 = lane & 15, lq = lane >> 4;
  int grp = blockIdx.x >> 5, rank = blockIdx.x & 31;
  int m = hh * 16 + l15;    // hidden col within slice (0..31)

  // load U slice (i8) into padded LDS: 128 cols x 1024
  {
    const char* src = Uq + (size_t)rank * 131072;
    #pragma unroll 4
    for (int i = 0; i < 64; ++i) {
      int o = i * 2048 + tid * 16;
      int c = o >> 10, k = o & 1023;
      *(uint4*)(Us + c * UCOL + k) = *(const uint4*)(src + o);
    }
  }
  __syncthreads();

  float s0 = su[rank * 128 + 0 * 32 + m];
  float s1 = su[rank * 128 + 1 * 32 + m];
  float s2 = su[rank * 128 + 2 * 32 + m];
  float s3 = su[rank * 128 + 3 * 32 + m];
  int bo0 = (0 * 32 + m) * UCOL + lq * 16;
  int bo1 = (1 * 32 + m) * UCOL + lq * 16;
  int bo2 = (2 * 32 + m) * UCOL + lq * 16;
  int bo3 = (3 * 32 + m) * UCOL + lq * 16;

  float cst[4] = {0.f, 0.f, 0.f, 0.f};
  float hst[4] = {0.f, 0.f, 0.f, 0.f};

  const char* xb = (const char*)xw +
      ((size_t)(grp * 16 + lq * 4) * TT * FH + rank * 128 + m * 4) * 2;

  unsigned voff = (unsigned)(l15 * 1024 + lq * 16);  // per-lane offset in group slab

  unsigned long long xg[4], xn[4];
  #pragma unroll
  for (int r = 0; r < 4; ++r) xg[r] = *(const unsigned long long*)(xb + (size_t)r * RSTRIDE);

  for (int t = 0; t < TT; ++t) {
    int tn = (t + 1) & 255;
    #pragma unroll
    for (int r = 0; r < 4; ++r)
      xn[r] = *(const unsigned long long*)(xb + (size_t)r * RSTRIDE + (size_t)tn * (FH * 2));
    unsigned long long mb = mask64[t];

    i32x4 aI = {0,0,0,0}, aF = {0,0,0,0}, aG = {0,0,0,0}, aO = {0,0,0,0};

    if (t > 0) {
      const char* hb = hseq + (size_t)(t - 1) * 65536 + (size_t)grp * 16384;
      uint4 A0, A1, A2, A3, A4, A5, A6, A7, A8, A9, A10, A11, A12, A13, A14, A15;
      for (;;) {
        asm volatile(
          "global_load_dwordx4 %0, %16, %17 sc0 sc1\n\t"
          "global_load_dwordx4 %1, %16, %17 offset:64 sc0 sc1\n\t"
          "global_load_dwordx4 %2, %16, %17 offset:128 sc0 sc1\n\t"
          "global_load_dwordx4 %3, %16, %17 offset:192 sc0 sc1\n\t"
          "global_load_dwordx4 %4, %16, %17 offset:256 sc0 sc1\n\t"
          "global_load_dwordx4 %5, %16, %17 offset:320 sc0 sc1\n\t"
          "global_load_dwordx4 %6, %16, %17 offset:384 sc0 sc1\n\t"
          "global_load_dwordx4 %7, %16, %17 offset:448 sc0 sc1\n\t"
          "global_load_dwordx4 %8, %16, %17 offset:512 sc0 sc1\n\t"
          "global_load_dwordx4 %9, %16, %17 offset:576 sc0 sc1\n\t"
          "global_load_dwordx4 %10, %16, %17 offset:640 sc0 sc1\n\t"
          "global_load_dwordx4 %11, %16, %17 offset:704 sc0 sc1\n\t"
          "global_load_dwordx4 %12, %16, %17 offset:768 sc0 sc1\n\t"
          "global_load_dwordx4 %13, %16, %17 offset:832 sc0 sc1\n\t"
          "global_load_dwordx4 %14, %16, %17 offset:896 sc0 sc1\n\t"
          "global_load_dwordx4 %15, %16, %17 offset:960 sc0 sc1\n\t"
          "s_waitcnt vmcnt(0)"
          : "=&v"(A0), "=&v"(A1), "=&v"(A2), "=&v"(A3),
            "=&v"(A4), "=&v"(A5), "=&v"(A6), "=&v"(A7),
            "=&v"(A8), "=&v"(A9), "=&v"(A10), "=&v"(A11),
            "=&v"(A12), "=&v"(A13), "=&v"(A14), "=&v"(A15)
          : "v"(voff), "s"(hb)
          : "memory");
        unsigned mn = 0xFFFFFFFFu;
        CHK(A0);  CHK(A1);  CHK(A2);  CHK(A3);
        CHK(A4);  CHK(A5);  CHK(A6);  CHK(A7);
        CHK(A8);  CHK(A9);  CHK(A10); CHK(A11);
        CHK(A12); CHK(A13); CHK(A14); CHK(A15);
        if (__all(mn != 0)) break;
        __builtin_amdgcn_s_sleep(1);
      }
      MFMA1(A0, 0);   MFMA1(A1, 1);   MFMA1(A2, 2);   MFMA1(A3, 3);
      MFMA1(A4, 4);   MFMA1(A5, 5);   MFMA1(A6, 6);   MFMA1(A7, 7);
      MFMA1(A8, 8);   MFMA1(A9, 9);   MFMA1(A10, 10); MFMA1(A11, 11);
      MFMA1(A12, 12); MFMA1(A13, 13); MFMA1(A14, 14); MFMA1(A15, 15);
    }

    GATE(0); GATE(1); GATE(2); GATE(3);

    // pack wave's 16x16 i8 block and store (u32/lane); no drain, no flag
    asm volatile("s_waitcnt lgkmcnt(0)" ::: "memory");
    {
      int prow = lane >> 2, pch = lane & 3;
      unsigned pv = *(const unsigned*)(hs + hh * 320 + prow * 20 + pch * 4);
      __hip_atomic_store(
          (unsigned*)(hseq + (size_t)t * 65536 + (size_t)(grp * 16 + prow) * 1024 +
                      rank * 32 + hh * 16 + pch * 4),
          pv, __ATOMIC_RELAXED, __HIP_MEMORY_SCOPE_AGENT);
    }

    xg[0] = xn[0]; xg[1] = xn[1]; xg[2] = xn[2]; xg[3] = xn[3];
  }
}

// ---------------- VAE head ----------------

__global__ void k_final(const float* __restrict__ hfin, const float* __restrict__ Wm,
                        const float* __restrict__ bm, const float* __restrict__ Wv,
                        const float* __restrict__ bv, const float* __restrict__ eps,
                        float* __restrict__ out) {
  int jb = blockIdx.x;
  int b = threadIdx.x & 63, u = threadIdx.x >> 6;
  int c0 = jb * 16 + u * 4;
  float am[4] = {0.f, 0.f, 0.f, 0.f};
  float av[4] = {0.f, 0.f, 0.f, 0.f};
  const float* hb = hfin + b * 1024;
  #pragma unroll 2
  for (int k = 0; k < 1024; ++k) {
    float hv = hb[k];
    float4 wm = *(const float4*)(Wm + (size_t)k * 1024 + c0);
    float4 wv = *(const float4*)(Wv + (size_t)k * 1024 + c0);
    am[0] += hv * wm.x; am[1] += hv * wm.y; am[2] += hv * wm.z; am[3] += hv * wm.w;
    av[0] += hv * wv.x; av[1] += hv * wv.y; av[2] += hv * wv.z; av[3] += hv * wv.w;
  }
  #pragma unroll
  for (int i = 0; i < 4; ++i) {
    int c = c0 + i;
    float mean = am[i] + bm[c];
    float lv = av[i] + bv[c];
    out[b * 1024 + c] = eps[b * 1024 + c] * __expf(0.5f * lv) + mean;
  }
}

// ---------------- launch ----------------

extern "C" void kernel_launch(void* const* d_in, const int* in_sizes, int n_in,
                              void* d_out, int out_size, void* d_ws, size_t ws_size,
                              hipStream_t stream) {
  const int*   tok = (const int*)d_in[0];
  const float* emb = (const float*)d_in[1];
  const float* W   = (const float*)d_in[2];
  const float* U   = (const float*)d_in[3];
  const float* bia = (const float*)d_in[4];
  const float* Wm  = (const float*)d_in[5];
  const float* bm  = (const float*)d_in[6];
  const float* Wv  = (const float*)d_in[7];
  const float* bv  = (const float*)d_in[8];
  const float* eps = (const float*)d_in[9];
  float* out = (float*)d_out;

  char* ws = (char*)d_ws;
  size_t off = 0;
  auto alloc = [&](size_t sz) { char* p = ws + off; off += (sz + 255) & ~(size_t)255; return p; };
  unsigned short* embb = (unsigned short*)alloc((size_t)VV * DD * 2);
  unsigned short* Wt   = (unsigned short*)alloc((size_t)FH * DD * 2);
  char*  Uq            = (char*)alloc((size_t)32 * 131072);
  float* su            = (float*)alloc((size_t)FH * 4);
  unsigned short* xw   = (unsigned short*)alloc((size_t)BB * TT * FH * 2);
  char*  hseq          = (char*)alloc((size_t)TT * 65536);
  unsigned long long* mask64 = (unsigned long long*)alloc((size_t)TT * 8);
  float* hfin          = (float*)alloc((size_t)BB * HH * 4);
  (void)in_sizes; (void)n_in; (void)out_size; (void)ws_size;

  (void)hipMemsetAsync(hseq, 0x80, (size_t)TT * 65536, stream);
  k_cast_emb<<<8000, 256, 0, stream>>>(emb, embb);
  k_prep_w<<<4096, 128, 0, stream>>>(W, Wt);
  k_prep_uq<<<4096, 256, 0, stream>>>(U, Uq, su);
  k_mask<<<1, 256, 0, stream>>>(tok, mask64);
  k_gemm_xw<<<4096, 256, 0, stream>>>(tok, embb, Wt, bia, xw);
  (void)hipFuncSetAttribute((const void*)k_lstm, hipFuncAttributeMaxDynamicSharedMemorySize, LSTM_LDS);
  k_lstm<<<128, 128, LSTM_LDS, stream>>>(Uq, su, xw, mask64, hseq, hfin);
  k_final<<<64, 256, 0, stream>>>(hfin, Wm, bm, Wv, bv, eps, out);
}

// Round 16
// 1689.056 us; speedup vs baseline: 1.2388x; 1.2388x over previous
//
#include <hip/hip_runtime.h>
#include <stdint.h>

#define BB 64
#define TT 256
#define VV 32000
#define DD 512
#define HH 1024
#define FH 4096

#define UCOL 1040                 // padded LDS col stride (i8, 1024+16)
#define ULDS (128 * UCOL)         // 133120
#define LSTM_LDS (ULDS + 1024)
#define RSTRIDE (TT * FH * 2)

typedef float f32x4 __attribute__((ext_vector_type(4)));
typedef int   i32x4 __attribute__((ext_vector_type(4)));
typedef __bf16 bf16x8 __attribute__((ext_vector_type(8)));

typedef __attribute__((address_space(1))) void void_g;
typedef __attribute__((address_space(3))) void void_l;

static __device__ __forceinline__ void gload_lds16(const void* g, void* l) {
  __builtin_amdgcn_global_load_lds((const void_g*)g, (void_l*)l, 16, 0, 0);
}

static __device__ __forceinline__ unsigned short f2bf(float f) {
  union { float f; unsigned u; } x; x.f = f;
  unsigned r = x.u + 0x7FFFu + ((x.u >> 16) & 1u);
  return (unsigned short)(r >> 16);
}
static __device__ __forceinline__ float bf2f(unsigned short s) {
  union { unsigned u; float f; } x; x.u = ((unsigned)s) << 16;
  return x.f;
}
static __device__ __forceinline__ i32x4 as_i32x4(uint4 v) {
  union { uint4 u; i32x4 i; } x; x.u = v; return x.i;
}
static __device__ __forceinline__ float sigm(float x) {
  return 1.f / (1.f + __expf(-x));
}
static __device__ __forceinline__ float tanh_f(float x) {
  x = fminf(15.f, fmaxf(-15.f, x));
  float e = __expf(2.f * x);
  return (e - 1.f) / (e + 1.f);
}

// ---------------- prep kernels ----------------

__global__ void k_cast_emb(const float* __restrict__ src, unsigned short* __restrict__ dst) {
  size_t i = ((size_t)blockIdx.x * 256 + threadIdx.x) * 8;
  float4 a = *(const float4*)(src + i);
  float4 b = *(const float4*)(src + i + 4);
  uint4 o;
  o.x = (unsigned)f2bf(a.x) | ((unsigned)f2bf(a.y) << 16);
  o.y = (unsigned)f2bf(a.z) | ((unsigned)f2bf(a.w) << 16);
  o.z = (unsigned)f2bf(b.x) | ((unsigned)f2bf(b.y) << 16);
  o.w = (unsigned)f2bf(b.z) | ((unsigned)f2bf(b.w) << 16);
  *(uint4*)(dst + i) = o;
}

// Plain transpose: Wt[n][k] bf16
__global__ void k_prep_w(const float* __restrict__ Wsrc, unsigned short* __restrict__ Wt) {
  int n = blockIdx.x;
  int k0 = threadIdx.x * 4;
  unsigned short q0 = f2bf(Wsrc[(size_t)(k0 + 0) * FH + n]);
  unsigned short q1 = f2bf(Wsrc[(size_t)(k0 + 1) * FH + n]);
  unsigned short q2 = f2bf(Wsrc[(size_t)(k0 + 2) * FH + n]);
  unsigned short q3 = f2bf(Wsrc[(size_t)(k0 + 3) * FH + n]);
  uint2 o;
  o.x = (unsigned)q0 | ((unsigned)q1 << 16);
  o.y = (unsigned)q2 | ((unsigned)q3 << 16);
  *(uint2*)((char*)Wt + (size_t)n * 1024 + (size_t)k0 * 2) = o;
}

// U int8 per-column quantization. Slice s (0..31), local col c (0..127):
// c = g*32 + m ; hidden = s*32 + m ; source col n = g*1024 + s*32 + m.
// Uq[s][c][k] i8 (col stride 1024), su[s*128+c] = maxcol / 127^2.
__global__ void k_prep_uq(const float* __restrict__ Usrc, char* __restrict__ Uq,
                          float* __restrict__ su) {
  __shared__ float red[4];
  int bid = blockIdx.x;
  int s = bid >> 7, c = bid & 127;
  int g = c >> 5, m = c & 31;
  int n = g * 1024 + s * 32 + m;
  int tid = threadIdx.x, lane = tid & 63, wid = tid >> 6;
  float v[4];
  float mx = 0.f;
  #pragma unroll
  for (int j = 0; j < 4; ++j) {
    v[j] = Usrc[(size_t)(tid * 4 + j) * FH + n];
    mx = fmaxf(mx, fabsf(v[j]));
  }
  #pragma unroll
  for (int off = 32; off; off >>= 1) mx = fmaxf(mx, __shfl_xor(mx, off));
  if (lane == 0) red[wid] = mx;
  __syncthreads();
  mx = fmaxf(fmaxf(red[0], red[1]), fmaxf(red[2], red[3]));
  float inv = mx > 0.f ? 127.f / mx : 0.f;
  unsigned pk = 0;
  #pragma unroll
  for (int j = 0; j < 4; ++j) {
    int q = __float2int_rn(v[j] * inv);
    pk |= ((unsigned)q & 255u) << (8 * j);
  }
  *(unsigned*)(Uq + (size_t)s * 131072 + (size_t)c * 1024 + tid * 4) = pk;
  if (tid == 0) su[s * 128 + c] = mx / 16129.f;
}

__global__ void k_mask(const int* __restrict__ tok, unsigned long long* __restrict__ mask64) {
  int t = threadIdx.x;
  unsigned long long m = 0;
  for (int b = 0; b < BB; ++b)
    m |= (unsigned long long)(tok[b * TT + t] != 0) << b;
  mask64[t] = m;
}

// ---------------- xW GEMM (gather fused) ----------------
// Output permuted: p = s*128 + m*4 + g  (4 gates adjacent per hidden)

__launch_bounds__(256)
__global__ void k_gemm_xw(const int* __restrict__ tok, const unsigned short* __restrict__ embb,
                          const unsigned short* __restrict__ Wt, const float* __restrict__ bsrc,
                          unsigned short* __restrict__ xw) {
  __shared__ char As[16384];
  __shared__ char Bs[16384];
  __shared__ int toks[128];
  int tid = threadIdx.x, lane = tid & 63, wid = tid >> 6;
  int bm = blockIdx.x >> 5, bn = blockIdx.x & 31;
  if (tid < 128) toks[tid] = tok[bm * 128 + tid];
  int wm = wid >> 1, wn = wid & 1;
  f32x4 vz = {0.f, 0.f, 0.f, 0.f};
  f32x4 acc[4][4];
  #pragma unroll
  for (int i = 0; i < 4; ++i)
    #pragma unroll
    for (int j = 0; j < 4; ++j) acc[i][j] = vz;

  int kls = (lane >> 4) * 16;
  for (int ks = 0; ks < 8; ++ks) {
    __syncthreads();
    #pragma unroll
    for (int c = 0; c < 4; ++c) {
      int o = wid * 4096 + c * 1024 + lane * 16;
      int m = o >> 7, kl = o & 127;
      const char* ga = (const char*)embb + (size_t)toks[m] * 1024 + ks * 128 + (kl ^ ((m & 7) << 4));
      gload_lds16(ga, As + o);
      const char* gb = (const char*)Wt + (size_t)(bn * 128 + m) * 1024 + ks * 128 + (kl ^ ((m & 7) << 4));
      gload_lds16(gb, Bs + o);
    }
    asm volatile("s_waitcnt vmcnt(0)" ::: "memory");
    __syncthreads();
    #pragma unroll
    for (int tk = 0; tk < 2; ++tk) {
      bf16x8 af[4], bf[4];
      int kb = tk * 64 + kls;
      #pragma unroll
      for (int mt = 0; mt < 4; ++mt) {
        int m = wm * 64 + mt * 16 + (lane & 15);
        af[mt] = *(const bf16x8*)(As + m * 128 + (kb ^ ((m & 7) << 4)));
      }
      #pragma unroll
      for (int nt = 0; nt < 4; ++nt) {
        int n = wn * 64 + nt * 16 + (lane & 15);
        bf[nt] = *(const bf16x8*)(Bs + n * 128 + (kb ^ ((n & 7) << 4)));
      }
      #pragma unroll
      for (int mt = 0; mt < 4; ++mt)
        #pragma unroll
        for (int nt = 0; nt < 4; ++nt)
          acc[mt][nt] = __builtin_amdgcn_mfma_f32_16x16x32_bf16(af[mt], bf[nt], acc[mt][nt], 0, 0, 0);
    }
  }
  #pragma unroll
  for (int nt = 0; nt < 4; ++nt) {
    int n = bn * 128 + wn * 64 + nt * 16 + (lane & 15);
    float bias = bsrc[n];
    int g = n >> 10, hid = n & 1023, s = hid >> 5, m = hid & 31;
    int p = s * 128 + m * 4 + g;
    #pragma unroll
    for (int mt = 0; mt < 4; ++mt) {
      #pragma unroll
      for (int r = 0; r < 4; ++r) {
        int row = bm * 128 + wm * 64 + mt * 16 + (lane >> 4) * 4 + r;
        xw[(size_t)row * FH + p] = f2bf(acc[mt][nt][r] + bias);
      }
    }
  }
}

// ---------------- persistent LSTM scan: 4 groups x 32 WGs, piecewise ------
// R14 protocol (best so far) with ONE change: each flag lives on its own
// 64B cache line (1 writer per line; polls spread over 8 lines/piece)
// to kill flag-line bouncing between 64 producers and 64 consumers.

#define GATE(R) do { \
  unsigned long long x_ = xg[R]; \
  float zi_ = (float)aI[R] * s0 + bf2f((unsigned short)(x_ & 0xFFFFu)); \
  float zf_ = (float)aF[R] * s1 + bf2f((unsigned short)((x_ >> 16) & 0xFFFFu)); \
  float zg_ = (float)aG[R] * s2 + bf2f((unsigned short)((x_ >> 32) & 0xFFFFu)); \
  float zo_ = (float)aO[R] * s3 + bf2f((unsigned short)((x_ >> 48) & 0xFFFFu)); \
  float I_ = sigm(zi_), F_ = sigm(zf_), G_ = tanh_f(zg_), O_ = sigm(zo_); \
  float cn_ = F_ * cst[R] + I_ * G_; \
  float hn_ = O_ * tanh_f(cn_); \
  if (!((mb >> (grp * 16 + lq * 4 + (R))) & 1ull)) { cn_ = cst[R]; hn_ = hst[R]; } \
  cst[R] = cn_; hst[R] = hn_; \
  hs[hh * 320 + (lq * 4 + (R)) * 20 + l15] = (char)__float2int_rn(hn_ * 127.f); \
  if (t == TT - 1) hfin[(size_t)(grp * 16 + lq * 4 + (R)) * 1024 + rank * 32 + hh * 16 + l15] = hn_; \
} while (0)

#define POLL8(P) do { \
  for (;;) { \
    unsigned v_ = __hip_atomic_load(fl + (size_t)((P) * 8 + (lane & 7)) * 16, \
                                    __ATOMIC_RELAXED, __HIP_MEMORY_SCOPE_AGENT); \
    if (__all(v_ != 0)) break; \
    __builtin_amdgcn_s_sleep(1); \
  } \
  asm volatile("" ::: "memory"); \
} while (0)

#define ISSUE(B, P) do { \
  B[0] = *(const uint4*)(hp + ((P) * 2 + 0) * 64); \
  B[1] = *(const uint4*)(hp + ((P) * 2 + 1) * 64); \
} while (0)

#define MFMA2(B, P) do { \
  _Pragma("unroll") \
  for (int q_ = 0; q_ < 2; ++q_) { \
    int u_ = (P) * 2 + q_; \
    i32x4 a_ = as_i32x4(B[q_]); \
    i32x4 b0_ = *(const i32x4*)(Us + bo0 + u_ * 64); \
    i32x4 b1_ = *(const i32x4*)(Us + bo1 + u_ * 64); \
    i32x4 b2_ = *(const i32x4*)(Us + bo2 + u_ * 64); \
    i32x4 b3_ = *(const i32x4*)(Us + bo3 + u_ * 64); \
    aI = __builtin_amdgcn_mfma_i32_16x16x64_i8(a_, b0_, aI, 0, 0, 0); \
    aF = __builtin_amdgcn_mfma_i32_16x16x64_i8(a_, b1_, aF, 0, 0, 0); \
    aG = __builtin_amdgcn_mfma_i32_16x16x64_i8(a_, b2_, aG, 0, 0, 0); \
    aO = __builtin_amdgcn_mfma_i32_16x16x64_i8(a_, b3_, aO, 0, 0, 0); \
  } \
} while (0)

__launch_bounds__(128, 1)
__global__ void k_lstm(const char* __restrict__ Uq, const float* __restrict__ su,
                       const unsigned short* __restrict__ xw,
                       const unsigned long long* __restrict__ mask64,
                       char* __restrict__ hseq, unsigned* __restrict__ flags,
                       float* __restrict__ hfin) {
  extern __shared__ char smem[];
  char* Us = smem;
  char* hs = smem + ULDS;   // [2 waves][16 rows][20]
  int tid = threadIdx.x, lane = tid & 63, hh = tid >> 6;
  int l15 = lane & 15, lq = lane >> 4;
  int grp = blockIdx.x >> 5, rank = blockIdx.x & 31;
  int m = hh * 16 + l15;    // hidden col within slice (0..31)

  // load U slice (i8) into padded LDS: 128 cols x 1024
  {
    const char* src = Uq + (size_t)rank * 131072;
    #pragma unroll 4
    for (int i = 0; i < 64; ++i) {
      int o = i * 2048 + tid * 16;
      int c = o >> 10, k = o & 1023;
      *(uint4*)(Us + c * UCOL + k) = *(const uint4*)(src + o);
    }
  }
  __syncthreads();

  float s0 = su[rank * 128 + 0 * 32 + m];
  float s1 = su[rank * 128 + 1 * 32 + m];
  float s2 = su[rank * 128 + 2 * 32 + m];
  float s3 = su[rank * 128 + 3 * 32 + m];
  int bo0 = (0 * 32 + m) * UCOL + lq * 16;
  int bo1 = (1 * 32 + m) * UCOL + lq * 16;
  int bo2 = (2 * 32 + m) * UCOL + lq * 16;
  int bo3 = (3 * 32 + m) * UCOL + lq * 16;

  float cst[4] = {0.f, 0.f, 0.f, 0.f};
  float hst[4] = {0.f, 0.f, 0.f, 0.f};

  const char* xb = (const char*)xw +
      ((size_t)(grp * 16 + lq * 4) * TT * FH + rank * 128 + m * 4) * 2;

  int p0v = rank >> 2;   // own piece first (own flags guaranteed set)
  int P0 = p0v,         P1 = (p0v+1)&7, P2 = (p0v+2)&7, P3 = (p0v+3)&7;
  int P4 = (p0v+4)&7,   P5 = (p0v+5)&7, P6 = (p0v+6)&7, P7 = (p0v+7)&7;

  unsigned long long xg[4], xn[4];
  #pragma unroll
  for (int r = 0; r < 4; ++r) xg[r] = *(const unsigned long long*)(xb + (size_t)r * RSTRIDE);

  for (int t = 0; t < TT; ++t) {
    int tn = (t + 1) & 255;
    #pragma unroll
    for (int r = 0; r < 4; ++r)
      xn[r] = *(const unsigned long long*)(xb + (size_t)r * RSTRIDE + (size_t)tn * (FH * 2));
    unsigned long long mb = mask64[t];

    i32x4 aI = {0,0,0,0}, aF = {0,0,0,0}, aG = {0,0,0,0}, aO = {0,0,0,0};

    if (t > 0) {
      const unsigned* fl = flags + ((size_t)(t - 1) * 256 + grp * 64) * 16;
      const char* hp = hseq + (size_t)(t - 1) * 65536 + (size_t)(grp * 16 + l15) * 1024 + lq * 16;
      uint4 B0[2], B1[2], B2[2];
      POLL8(P0); ISSUE(B0, P0);
      POLL8(P1); ISSUE(B1, P1);
      POLL8(P2); ISSUE(B2, P2); MFMA2(B0, P0);
      POLL8(P3); ISSUE(B0, P3); MFMA2(B1, P1);
      POLL8(P4); ISSUE(B1, P4); MFMA2(B2, P2);
      POLL8(P5); ISSUE(B2, P5); MFMA2(B0, P3);
      POLL8(P6); ISSUE(B0, P6); MFMA2(B1, P4);
      POLL8(P7); ISSUE(B1, P7); MFMA2(B2, P5);
      MFMA2(B0, P6);
      MFMA2(B1, P7);
    }

    GATE(0); GATE(1); GATE(2); GATE(3);

    // pack wave's 16x16 i8 block and store (u32/lane) to the step buffer
    asm volatile("s_waitcnt lgkmcnt(0)" ::: "memory");
    {
      int prow = lane >> 2, pch = lane & 3;
      unsigned pv = *(const unsigned*)(hs + hh * 320 + prow * 20 + pch * 4);
      __hip_atomic_store(
          (unsigned*)(hseq + (size_t)t * 65536 + (size_t)(grp * 16 + prow) * 1024 +
                      rank * 32 + hh * 16 + pch * 4),
          pv, __ATOMIC_RELAXED, __HIP_MEMORY_SCOPE_AGENT);
    }
    asm volatile("s_waitcnt vmcnt(0)" ::: "memory");
    if (lane == 0)
      __hip_atomic_store(flags + ((size_t)t * 256 + grp * 64 + rank * 2 + hh) * 16, 1u,
                         __ATOMIC_RELAXED, __HIP_MEMORY_SCOPE_AGENT);

    xg[0] = xn[0]; xg[1] = xn[1]; xg[2] = xn[2]; xg[3] = xn[3];
  }
}

// ---------------- VAE head ----------------

__global__ void k_final(const float* __restrict__ hfin, const float* __restrict__ Wm,
                        const float* __restrict__ bm, const float* __restrict__ Wv,
                        const float* __restrict__ bv, const float* __restrict__ eps,
                        float* __restrict__ out) {
  int jb = blockIdx.x;
  int b = threadIdx.x & 63, u = threadIdx.x >> 6;
  int c0 = jb * 16 + u * 4;
  float am[4] = {0.f, 0.f, 0.f, 0.f};
  float av[4] = {0.f, 0.f, 0.f, 0.f};
  const float* hb = hfin + b * 1024;
  #pragma unroll 2
  for (int k = 0; k < 1024; ++k) {
    float hv = hb[k];
    float4 wm = *(const float4*)(Wm + (size_t)k * 1024 + c0);
    float4 wv = *(const float4*)(Wv + (size_t)k * 1024 + c0);
    am[0] += hv * wm.x; am[1] += hv * wm.y; am[2] += hv * wm.z; am[3] += hv * wm.w;
    av[0] += hv * wv.x; av[1] += hv * wv.y; av[2] += hv * wv.z; av[3] += hv * wv.w;
  }
  #pragma unroll
  for (int i = 0; i < 4; ++i) {
    int c = c0 + i;
    float mean = am[i] + bm[c];
    float lv = av[i] + bv[c];
    out[b * 1024 + c] = eps[b * 1024 + c] * __expf(0.5f * lv) + mean;
  }
}

// ---------------- launch ----------------

extern "C" void kernel_launch(void* const* d_in, const int* in_sizes, int n_in,
                              void* d_out, int out_size, void* d_ws, size_t ws_size,
                              hipStream_t stream) {
  const int*   tok = (const int*)d_in[0];
  const float* emb = (const float*)d_in[1];
  const float* W   = (const float*)d_in[2];
  const float* U   = (const float*)d_in[3];
  const float* bia = (const float*)d_in[4];
  const float* Wm  = (const float*)d_in[5];
  const float* bm  = (const float*)d_in[6];
  const float* Wv  = (const float*)d_in[7];
  const float* bv  = (const float*)d_in[8];
  const float* eps = (const float*)d_in[9];
  float* out = (float*)d_out;

  char* ws = (char*)d_ws;
  size_t off = 0;
  auto alloc = [&](size_t sz) { char* p = ws + off; off += (sz + 255) & ~(size_t)255; return p; };
  unsigned short* embb = (unsigned short*)alloc((size_t)VV * DD * 2);
  unsigned short* Wt   = (unsigned short*)alloc((size_t)FH * DD * 2);
  char*  Uq            = (char*)alloc((size_t)32 * 131072);
  float* su            = (float*)alloc((size_t)FH * 4);
  unsigned short* xw   = (unsigned short*)alloc((size_t)BB * TT * FH * 2);
  char*  hseq          = (char*)alloc((size_t)TT * 65536);
  unsigned* flags      = (unsigned*)alloc((size_t)TT * 256 * 64);
  unsigned long long* mask64 = (unsigned long long*)alloc((size_t)TT * 8);
  float* hfin          = (float*)alloc((size_t)BB * HH * 4);
  (void)in_sizes; (void)n_in; (void)out_size; (void)ws_size;

  (void)hipMemsetAsync(flags, 0, (size_t)TT * 256 * 64, stream);
  k_cast_emb<<<8000, 256, 0, stream>>>(emb, embb);
  k_prep_w<<<4096, 128, 0, stream>>>(W, Wt);
  k_prep_uq<<<4096, 256, 0, stream>>>(U, Uq, su);
  k_mask<<<1, 256, 0, stream>>>(tok, mask64);
  k_gemm_xw<<<4096, 256, 0, stream>>>(tok, embb, Wt, bia, xw);
  (void)hipFuncSetAttribute((const void*)k_lstm, hipFuncAttributeMaxDynamicSharedMemorySize, LSTM_LDS);
  k_lstm<<<128, 128, LSTM_LDS, stream>>>(Uq, su, xw, mask64, hseq, flags, hfin);
  k_final<<<64, 256, 0, stream>>>(hfin, Wm, bm, Wv, bv, eps, out);
}